// Round 8
// baseline (130.881 us; speedup 1.0000x reference)
//
#include <hip/hip_runtime.h>

// Problem constants
#define BATCH 64
#define NNODE 1024
#define FDIM  200
#define MROWS (BATCH * NNODE)   // 65536
#define NEG_SLOPE 0.2f

#define NKT 7                   // k-tiles of 32 for W-GEMM (K 200 -> 224)
#define NNT 13                  // n-tiles of 16 (N 200 -> 208)
#define NTP 7                   // nt-PAIRS per i-tile in k_attn (last is single)

typedef short s16x8 __attribute__((ext_vector_type(8)));
typedef float f32x4 __attribute__((ext_vector_type(4)));

// ws layout (bytes):
//   h0frag : bf16 B-fragments of h0, 32 kt2 x 13 nt x 1024 B   [0, 425984)
//   a_s    : float[1024]  @ 425984
//   a_d    : float[1024]  @ 430080
//   fragW  : bf16 B-fragments of W, 7 kt x 13 nt x 1024 B @ 442368 (93,184 B)
//   wsv    : float[200] @ 535552   (W @ att_src)
//   wdv    : float[200] @ 536352   (W @ att_dst)

__device__ __forceinline__ unsigned int f2bf(float f) {
    unsigned int u = __float_as_uint(f);
    return (u + 0x7fffu + ((u >> 16) & 1u)) >> 16;
}
__device__ __forceinline__ unsigned int pack2(float a, float b) {
    return f2bf(a) | (f2bf(b) << 16);
}
__device__ __forceinline__ float lrelu(float s) {
    return (s > 0.f) ? s : NEG_SLOPE * s;
}

// ---------------------------------------------------------------------------
// k_prep: blocks 0..90  : W -> bf16 B-fragments (16x16x32 layout), 224x208 pad
//         blocks 91..290: wsv[k]/wdv[k] = dot(W[k,:], att_src/att_dst)
// ---------------------------------------------------------------------------
__global__ __launch_bounds__(64) void k_prep(const float* __restrict__ W,
                                             const float* __restrict__ att_src,
                                             const float* __restrict__ att_dst,
                                             unsigned short* __restrict__ fragW,
                                             float* __restrict__ wsv,
                                             float* __restrict__ wdv)
{
    const int b    = blockIdx.x;
    const int lane = threadIdx.x;

    if (b < 91) {
        const int kt   = b / NNT;
        const int nt   = b - kt * NNT;
        const int n    = nt * 16 + (lane & 15);
        const int kb   = kt * 32 + (lane >> 4) * 8;
        s16x8 v;
        #pragma unroll
        for (int j = 0; j < 8; ++j) {
            int k = kb + j;
            float f = (k < FDIM && n < FDIM) ? W[k * FDIM + n] : 0.f;
            v[j] = (short)f2bf(f);
        }
        ((s16x8*)(fragW + (size_t)b * 512))[lane] = v;
    } else {
        const int kk = b - 91;               // [0, 200)
        const float* Wr = W + kk * FDIM;
        float ps = 0.f, pd = 0.f;
        #pragma unroll
        for (int i = 0; i < 4; ++i) {
            int n = lane + i * 64;
            if (n < FDIM) {
                float wv = Wr[n];
                ps = fmaf(wv, att_src[n], ps);
                pd = fmaf(wv, att_dst[n], pd);
            }
        }
        #pragma unroll
        for (int off = 32; off; off >>= 1) {
            ps += __shfl_down(ps, off);
            pd += __shfl_down(pd, off);
        }
        if (lane == 0) { wsv[kk] = ps; wdv[kk] = pd; }
    }
}

// ---------------------------------------------------------------------------
// k_gemm: h = x @ W, N-SPLIT for occupancy. 1024 blocks x 512 thr (8 waves x
// 16 rows = 128 rows). Block bid: row-group rgrp = bid>>1 (128 rows), column
// half = bid&1 (A: nt 0..6, B: nt 7..12). LDS = 50.2/43 KB + 8.5 KB scratch
// -> 2 blocks/CU (vs 1 with whole-fragW), 16 waves/CU, 4 waves/SIMD: double
// the latency-hiding TLP of the R6 version (which profiled at 45.5us with
// Occupancy 16%, everything idle). Each half stages its 49/42 fragment
// groups once, single barrier, barrier-free K-loop. x is read by both
// halves; x (52 MB) is L3-resident so the HBM re-fetch cost is small.
//   rgrp >= 8: out = h + bias.
//   rgrp <  8: h -> h0frag (own nt range); half A also computes a_s/a_d.
// ---------------------------------------------------------------------------
template<int NTBASE, int NTLOC>
__device__ __forceinline__ void gemm_half(const float* __restrict__ x,
                                          const unsigned short* __restrict__ fragW,
                                          const float* __restrict__ bias,
                                          const float* __restrict__ wsv,
                                          const float* __restrict__ wdv,
                                          float* __restrict__ out,
                                          unsigned short* __restrict__ h0frag,
                                          float* __restrict__ a_s,
                                          float* __restrict__ a_d,
                                          unsigned short* Bf, float* scr,
                                          int rgrp, int tid)
{
    const int lane = tid & 63;
    const int w    = __builtin_amdgcn_readfirstlane(tid >> 6);
    const int ln   = lane & 15;
    const int quad = lane >> 4;
    const int row0 = rgrp * 128 + w * 16;

    // ---- stage this half's fragment groups: g in [0, NKT*NTLOC), one
    // 1024-B group per wave per round (64 lanes x 16 B, linear dest).
    {
        constexpr int NG = NKT * NTLOC;
        #pragma unroll
        for (int r = 0; r < (NG + 7) / 8; ++r) {
            int g = r * 8 + w;
            if (g < NG) {
                const int kt = g / NTLOC, nl = g - kt * NTLOC;
                const char* gsrc = (const char*)fragW
                    + ((size_t)(kt * NNT + NTBASE + nl)) * 1024 + lane * 16;
                char* ldst = (char*)Bf + (size_t)g * 1024 + lane * 16;
                __builtin_amdgcn_global_load_lds(
                    (const __attribute__((address_space(1))) void*)gsrc,
                    (__attribute__((address_space(3))) void*)ldst, 16, 0, 0);
            }
        }
    }

    // ---- all 7 A k-tiles -> registers (drained by the barrier below).
    const float* xrow = x + (size_t)(row0 + ln) * FDIM;
    float4 ar[NKT][2];
    #pragma unroll
    for (int kt = 0; kt < NKT; ++kt) {
        if (kt < 6) {
            const float4* ap = (const float4*)(xrow + kt * 32 + quad * 8);
            ar[kt][0] = ap[0]; ar[kt][1] = ap[1];
        } else if (quad == 0) {
            const float4* ap = (const float4*)(xrow + kt * 32);
            ar[kt][0] = ap[0]; ar[kt][1] = ap[1];
        } else {
            ar[kt][0] = make_float4(0.f, 0.f, 0.f, 0.f);
            ar[kt][1] = make_float4(0.f, 0.f, 0.f, 0.f);
        }
    }

    f32x4 acc[NTLOC];
    #pragma unroll
    for (int nt = 0; nt < NTLOC; ++nt) acc[nt] = (f32x4){0.f, 0.f, 0.f, 0.f};

    __syncthreads();        // Bf + ar resident (only main-path barrier)

    // ---- barrier-free K-loop
    #pragma unroll
    for (int kt = 0; kt < NKT; ++kt) {
        float4 f0 = ar[kt][0], f1 = ar[kt][1];
        unsigned int au[4] = {pack2(f0.x, f0.y), pack2(f0.z, f0.w),
                              pack2(f1.x, f1.y), pack2(f1.z, f1.w)};
        s16x8 a = *(s16x8*)au;
        const unsigned short* bbase = Bf + kt * NTLOC * 512;
        #pragma unroll
        for (int nt = 0; nt < NTLOC; ++nt) {
            s16x8 b = *(const s16x8*)(bbase + nt * 512 + lane * 8);
            acc[nt] = __builtin_amdgcn_mfma_f32_16x16x32_bf16(a, b, acc[nt], 0, 0, 0);
        }
    }

    // D layout: col = (NTBASE+nt)*16 + ln, row = quad*4 + r
    if (rgrp >= 8) {
        #pragma unroll
        for (int nt = 0; nt < NTLOC; ++nt) {
            const int ntg = NTBASE + nt;
            int col = ntg * 16 + ln;
            if (ntg < 12 || ln < 8) {
                float bv = bias[col];
                #pragma unroll
                for (int r = 0; r < 4; ++r)
                    out[(size_t)(row0 + quad * 4 + r) * FDIM + col] = acc[nt][r] + bv;
            }
        }
    } else {
        // --- fused k_av (half A only): full-K dot from the A registers.
        if (NTBASE == 0) {
            float ps = 0.f, pd = 0.f;
            #pragma unroll
            for (int kt = 0; kt < NKT; ++kt) {
                if (kt < 6 || quad == 0) {
                    float4 f0 = ar[kt][0], f1 = ar[kt][1];
                    const float4* sp = (const float4*)(wsv + kt * 32 + quad * 8);
                    const float4* dp = (const float4*)(wdv + kt * 32 + quad * 8);
                    float4 s0 = sp[0], s1 = sp[1], d0 = dp[0], d1 = dp[1];
                    ps += f0.x*s0.x + f0.y*s0.y + f0.z*s0.z + f0.w*s0.w
                        + f1.x*s1.x + f1.y*s1.y + f1.z*s1.z + f1.w*s1.w;
                    pd += f0.x*d0.x + f0.y*d0.y + f0.z*d0.z + f0.w*d0.w
                        + f1.x*d1.x + f1.y*d1.y + f1.z*d1.z + f1.w*d1.w;
                }
            }
            ps += __shfl_down(ps, 32); ps += __shfl_down(ps, 16);
            pd += __shfl_down(pd, 32); pd += __shfl_down(pd, 16);
            if (lane < 16) {
                a_s[row0 + lane] = ps;
                a_d[row0 + lane] = pd;
            }
        }
        // --- h0frag: transpose C-layout -> bf16 B-fragment halves (own nt's).
        float* scrw = scr + w * (16 * 17);
        const int kt2 = row0 >> 5;
        const int lo  = (row0 >> 4) & 1;
        for (int nt = 0; nt < NTLOC; ++nt) {
            const int ntg = NTBASE + nt;
            #pragma unroll
            for (int r = 0; r < 4; ++r) scrw[(quad * 4 + r) * 17 + ln] = acc[nt][r];
            __syncthreads();
            if (lane < 32) {                   // half-frag: lane = oct*16 + n
                int oct = lane >> 4, nl = lane & 15;
                uint4 dv;
                dv.x = pack2(scrw[(oct * 8 + 0) * 17 + nl], scrw[(oct * 8 + 1) * 17 + nl]);
                dv.y = pack2(scrw[(oct * 8 + 2) * 17 + nl], scrw[(oct * 8 + 3) * 17 + nl]);
                dv.z = pack2(scrw[(oct * 8 + 4) * 17 + nl], scrw[(oct * 8 + 5) * 17 + nl]);
                dv.w = pack2(scrw[(oct * 8 + 6) * 17 + nl], scrw[(oct * 8 + 7) * 17 + nl]);
                *(uint4*)(h0frag + ((size_t)(kt2 * NNT + ntg) * 64 + lo * 32 + lane) * 8) = dv;
            }
            __syncthreads();
        }
    }
}

__global__ __launch_bounds__(512, 4) void k_gemm(const float* __restrict__ x,
                                                 const unsigned short* __restrict__ fragW,
                                                 const float* __restrict__ bias,
                                                 const float* __restrict__ wsv,
                                                 const float* __restrict__ wdv,
                                                 float* __restrict__ out,
                                                 unsigned short* __restrict__ h0frag,
                                                 float* __restrict__ a_s,
                                                 float* __restrict__ a_d)
{
    __shared__ __align__(16) unsigned short Bf[NKT * 7 * 512];   // 50,176 B
    __shared__ float scr[8][16 * 17];                            //  8,704 B
    const int tid  = threadIdx.x;
    const int rgrp = blockIdx.x >> 1;
    const int half = blockIdx.x & 1;

    if (half == 0)
        gemm_half<0, 7>(x, fragW, bias, wsv, wdv, out, h0frag, a_s, a_d,
                        &Bf[0], &scr[0][0], rgrp, tid);
    else
        gemm_half<7, 6>(x, fragW, bias, wsv, wdv, out, h0frag, a_s, a_d,
                        &Bf[0], &scr[0][0], rgrp, tid);
}

// ---------------------------------------------------------------------------
// k_attn: out0 = (alpha @ h0) + bias via MFMA. 448 blocks = 64 i-tiles x
// 7 nt-PAIRS (last pair is nt=12 alone). afrag shared by both nt of a pair.
// 4 waves, j-split 8 kt2 each, cross-wave LDS reduce, wave 0 stores.
// (UNCHANGED from R7.)
// ---------------------------------------------------------------------------
__global__ __launch_bounds__(256) void k_attn(const unsigned short* __restrict__ h0frag,
                                              const float* __restrict__ a_s,
                                              const float* __restrict__ a_d,
                                              const float* __restrict__ bias,
                                              float* __restrict__ out)
{
    __shared__ __align__(16) float as_s[1024];
    __shared__ float mls[16];           // per-row m
    __shared__ float rls[16];           // per-row 1/l
    __shared__ f32x4 red[2][3][64];     // [ntIdx][wave-1][lane]
    const int tid  = threadIdx.x;
    const int lane = tid & 63;
    const int w    = __builtin_amdgcn_readfirstlane(tid >> 6);
    const int ln   = lane & 15;
    const int quad = lane >> 4;
    const int it   = blockIdx.x / NTP;          // 0..63 (16-row i-tiles)
    const int p    = blockIdx.x - it * NTP;     // 0..6  (nt-pair)
    const int nt0  = p * 2;
    const int nt1  = p * 2 + 1;
    const bool has1 = (nt1 < NNT);              // block-uniform
    const int i0   = it * 16;

    #pragma unroll
    for (int i = 0; i < 4; ++i) as_s[tid + i * 256] = a_s[tid + i * 256];
    __syncthreads();

    // wave-redundant global max of a_s
    float mx = -1e30f;
    #pragma unroll
    for (int i = 0; i < 16; ++i) mx = fmaxf(mx, as_s[lane + i * 64]);
    #pragma unroll
    for (int off = 32; off; off >>= 1) mx = fmaxf(mx, __shfl_down(mx, off));
    mx = __shfl(mx, 0);

    // wave w: stats for rows w*4 .. w*4+3
    #pragma unroll
    for (int rr = 0; rr < 4; ++rr) {
        const int r  = w * 4 + rr;
        const float adr = a_d[i0 + r];
        const float mi  = lrelu(adr + mx);
        float sum = 0.f;
        #pragma unroll
        for (int i = 0; i < 16; ++i)
            sum += __expf(lrelu(adr + as_s[lane + i * 64]) - mi);
        #pragma unroll
        for (int off = 32; off; off >>= 1) sum += __shfl_down(sum, off);
        if (lane == 0) { mls[r] = mi; rls[r] = 1.0f / sum; }
    }
    __syncthreads();

    const float ad = a_d[i0 + ln];
    const float mi = mls[ln];

    f32x4 acc0A = (f32x4){0.f, 0.f, 0.f, 0.f};
    f32x4 acc0B = (f32x4){0.f, 0.f, 0.f, 0.f};
    f32x4 acc1A = (f32x4){0.f, 0.f, 0.f, 0.f};
    f32x4 acc1B = (f32x4){0.f, 0.f, 0.f, 0.f};

    #pragma unroll
    for (int k8 = 0; k8 < 8; ++k8) {
        const int kt2 = w * 8 + k8;             // wave's j-quarter
        const float4* ap = (const float4*)(as_s + kt2 * 32 + quad * 8);
        float4 f0 = ap[0], f1 = ap[1];
        float e[8] = {f0.x, f0.y, f0.z, f0.w, f1.x, f1.y, f1.z, f1.w};
        #pragma unroll
        for (int j = 0; j < 8; ++j)
            e[j] = __expf(lrelu(ad + e[j]) - mi);
        unsigned int au[4] = {pack2(e[0], e[1]), pack2(e[2], e[3]),
                              pack2(e[4], e[5]), pack2(e[6], e[7])};
        s16x8 afrag = *(s16x8*)au;              // shared by both nt!
        const unsigned short* bb = h0frag + ((size_t)(kt2 * NNT + nt0) * 64 + lane) * 8;
        s16x8 b0 = *(const s16x8*)bb;
        if (k8 & 1) acc0B = __builtin_amdgcn_mfma_f32_16x16x32_bf16(afrag, b0, acc0B, 0, 0, 0);
        else        acc0A = __builtin_amdgcn_mfma_f32_16x16x32_bf16(afrag, b0, acc0A, 0, 0, 0);
        if (has1) {
            s16x8 b1 = *(const s16x8*)(bb + 512);   // nt1 = nt0+1: +64*8 shorts
            if (k8 & 1) acc1B = __builtin_amdgcn_mfma_f32_16x16x32_bf16(afrag, b1, acc1B, 0, 0, 0);
            else        acc1A = __builtin_amdgcn_mfma_f32_16x16x32_bf16(afrag, b1, acc1A, 0, 0, 0);
        }
    }

    f32x4 acc0 = acc0A + acc0B;
    f32x4 acc1 = acc1A + acc1B;
    if (w > 0) { red[0][w - 1][lane] = acc0; red[1][w - 1][lane] = acc1; }
    __syncthreads();

    if (w == 0) {
        #pragma unroll
        for (int ww = 0; ww < 3; ++ww) { acc0 += red[0][ww][lane]; acc1 += red[1][ww][lane]; }
        {
            const int col = nt0 * 16 + ln;
            if (nt0 < 12 || ln < 8) {
                float bv = bias[col];
                #pragma unroll
                for (int r = 0; r < 4; ++r) {
                    float rl = rls[quad * 4 + r];
                    out[(size_t)(i0 + quad * 4 + r) * FDIM + col] = acc0[r] * rl + bv;
                }
            }
        }
        if (has1) {
            const int col = nt1 * 16 + ln;      // nt1 <= 11: always full 16 cols
            float bv = bias[col];
            #pragma unroll
            for (int r = 0; r < 4; ++r) {
                float rl = rls[quad * 4 + r];
                out[(size_t)(i0 + quad * 4 + r) * FDIM + col] = acc1[r] * rl + bv;
            }
        }
    }
}

// ---------------------------------------------------------------------------
extern "C" void kernel_launch(void* const* d_in, const int* in_sizes, int n_in,
                              void* d_out, int out_size, void* d_ws, size_t ws_size,
                              hipStream_t stream)
{
    const float* x       = (const float*)d_in[0];
    const float* W       = (const float*)d_in[1];
    const float* att_src = (const float*)d_in[2];
    const float* att_dst = (const float*)d_in[3];
    const float* bias    = (const float*)d_in[4];
    float* out = (float*)d_out;
    char*  wsb = (char*)d_ws;

    unsigned short* h0frag = (unsigned short*)(wsb + 0);       // 425,984 B
    float* a_s   = (float*)(wsb + 425984);
    float* a_d   = (float*)(wsb + 430080);
    unsigned short* fragW = (unsigned short*)(wsb + 442368);   // 93,184 B
    float* wsv   = (float*)(wsb + 535552);
    float* wdv   = (float*)(wsb + 536352);

    k_prep <<<291,            64, 0, stream>>>(W, att_src, att_dst, fragW, wsv, wdv);
    k_gemm <<<MROWS / 64,    512, 0, stream>>>(x, fragW, bias, wsv, wdv, out, h0frag, a_s, a_d);
    k_attn <<<64 * NTP,      256, 0, stream>>>(h0frag, a_s, a_d, bias, out);
}

// Round 9
// 123.835 us; speedup vs baseline: 1.0569x; 1.0569x over previous
//
#include <hip/hip_runtime.h>

// Problem constants
#define BATCH 64
#define NNODE 1024
#define FDIM  200
#define MROWS (BATCH * NNODE)   // 65536
#define NEG_SLOPE 0.2f

#define NKT 7                   // k-tiles of 32 for W-GEMM (K 200 -> 224)
#define NNT 13                  // n-tiles of 16 (N 200 -> 208)
#define FRAGW_BYTES (NKT * NNT * 1024)   // 93,184 B: ALL of fragW
#define NBLK 256                // persistent k_gemm blocks (1/CU); 2 tiles each

typedef short s16x8 __attribute__((ext_vector_type(8)));
typedef float f32x4 __attribute__((ext_vector_type(4)));

// ws layout (bytes):
//   h0frag : bf16 B-fragments of h0, 32 kt2 x 13 nt x 1024 B   [0, 425984)
//   a_s    : float[1024]  @ 425984
//   a_d    : float[1024]  @ 430080
//   fragW  : bf16 B-fragments of W, 7 kt x 13 nt x 1024 B @ 442368 (93,184 B)
//   wsv    : float[200] @ 535552   (W @ att_src)
//   wdv    : float[200] @ 536352   (W @ att_dst)

__device__ __forceinline__ unsigned int f2bf(float f) {
    unsigned int u = __float_as_uint(f);
    return (u + 0x7fffu + ((u >> 16) & 1u)) >> 16;
}
__device__ __forceinline__ unsigned int pack2(float a, float b) {
    return f2bf(a) | (f2bf(b) << 16);
}
__device__ __forceinline__ float lrelu(float s) {
    return (s > 0.f) ? s : NEG_SLOPE * s;
}

// ---------------------------------------------------------------------------
// k_prep: blocks 0..90  : W -> bf16 B-fragments (16x16x32 layout), 224x208 pad
//         blocks 91..290: wsv[k]/wdv[k] = dot(W[k,:], att_src/att_dst)
// ---------------------------------------------------------------------------
__global__ __launch_bounds__(64) void k_prep(const float* __restrict__ W,
                                             const float* __restrict__ att_src,
                                             const float* __restrict__ att_dst,
                                             unsigned short* __restrict__ fragW,
                                             float* __restrict__ wsv,
                                             float* __restrict__ wdv)
{
    const int b    = blockIdx.x;
    const int lane = threadIdx.x;

    if (b < 91) {
        const int kt   = b / NNT;
        const int nt   = b - kt * NNT;
        const int n    = nt * 16 + (lane & 15);
        const int kb   = kt * 32 + (lane >> 4) * 8;
        s16x8 v;
        #pragma unroll
        for (int j = 0; j < 8; ++j) {
            int k = kb + j;
            float f = (k < FDIM && n < FDIM) ? W[k * FDIM + n] : 0.f;
            v[j] = (short)f2bf(f);
        }
        ((s16x8*)(fragW + (size_t)b * 512))[lane] = v;
    } else {
        const int kk = b - 91;               // [0, 200)
        const float* Wr = W + kk * FDIM;
        float ps = 0.f, pd = 0.f;
        #pragma unroll
        for (int i = 0; i < 4; ++i) {
            int n = lane + i * 64;
            if (n < FDIM) {
                float wv = Wr[n];
                ps = fmaf(wv, att_src[n], ps);
                pd = fmaf(wv, att_dst[n], pd);
            }
        }
        #pragma unroll
        for (int off = 32; off; off >>= 1) {
            ps += __shfl_down(ps, off);
            pd += __shfl_down(pd, off);
        }
        if (lane == 0) { wsv[kk] = ps; wdv[kk] = pd; }
    }
}

// ---------------------------------------------------------------------------
// k_gemm: h = x @ W. PERSISTENT: 256 blocks x 512 thr (8 waves), one per CU;
// block b processes row-tiles t0 = b and t1 = b + 256 (128 rows each).
// fragW (93,184 B) staged to LDS ONCE and reused for both tiles. A-registers
// for t1 issued right after the single barrier so the x-stream for t1 rides
// under t0's compute. (R7-EXACT revert: the R8 N-split added ~26 MB of x
// re-fetch, which under fill-overlap costs wall time -- byte count governs.)
// ---------------------------------------------------------------------------
__global__ __launch_bounds__(512, 2) void k_gemm(const float* __restrict__ x,
                                                 const unsigned short* __restrict__ fragW,
                                                 const float* __restrict__ bias,
                                                 const float* __restrict__ wsv,
                                                 const float* __restrict__ wdv,
                                                 float* __restrict__ out,
                                                 unsigned short* __restrict__ h0frag,
                                                 float* __restrict__ a_s,
                                                 float* __restrict__ a_d)
{
    __shared__ __align__(16) unsigned short Bf[FRAGW_BYTES / 2];  // 93,184 B
    __shared__ float scr[8][16 * 17];                             //  8,704 B
    const int tid  = threadIdx.x;
    const int lane = tid & 63;
    const int w    = __builtin_amdgcn_readfirstlane(tid >> 6);
    const int ln   = lane & 15;
    const int quad = lane >> 4;
    const int row0 = blockIdx.x * 128 + w * 16;            // tile t0
    const int row1 = (blockIdx.x + NBLK) * 128 + w * 16;   // tile t1 (>=32768)

    // ---- stage ALL of fragW into LDS, linear 16 B/thread/round.
    {
        const char* gsrc = (const char*)fragW;
        char* ldst = (char*)&Bf[0];
        #pragma unroll
        for (int r = 0; r < 12; ++r) {
            int off = tid * 16 + r * 8192;
            if (off < FRAGW_BYTES)
                __builtin_amdgcn_global_load_lds(
                    (const __attribute__((address_space(1))) void*)(gsrc + off),
                    (__attribute__((address_space(3))) void*)(ldst + off),
                    16, 0, 0);
        }
    }

    // ---- A k-tiles for t0 -> registers (drained by the barrier below).
    const float* xrow0 = x + (size_t)(row0 + ln) * FDIM;
    const float* xrow1 = x + (size_t)(row1 + ln) * FDIM;
    float4 ar[NKT][2];
    #pragma unroll
    for (int kt = 0; kt < NKT; ++kt) {
        if (kt < 6) {
            const float4* ap = (const float4*)(xrow0 + kt * 32 + quad * 8);
            ar[kt][0] = ap[0]; ar[kt][1] = ap[1];
        } else if (quad == 0) {
            const float4* ap = (const float4*)(xrow0 + kt * 32);
            ar[kt][0] = ap[0]; ar[kt][1] = ap[1];
        } else {
            ar[kt][0] = make_float4(0.f, 0.f, 0.f, 0.f);
            ar[kt][1] = make_float4(0.f, 0.f, 0.f, 0.f);
        }
    }

    f32x4 acc[NNT];
    #pragma unroll
    for (int nt = 0; nt < NNT; ++nt) acc[nt] = (f32x4){0.f, 0.f, 0.f, 0.f};

    __syncthreads();        // Bf + ar resident after this (only block barrier)

    // ---- A k-tiles for t1: fire now, consumed after t0's compute+store.
    float4 ar2[NKT][2];
    #pragma unroll
    for (int kt = 0; kt < NKT; ++kt) {
        if (kt < 6) {
            const float4* ap = (const float4*)(xrow1 + kt * 32 + quad * 8);
            ar2[kt][0] = ap[0]; ar2[kt][1] = ap[1];
        } else if (quad == 0) {
            const float4* ap = (const float4*)(xrow1 + kt * 32);
            ar2[kt][0] = ap[0]; ar2[kt][1] = ap[1];
        } else {
            ar2[kt][0] = make_float4(0.f, 0.f, 0.f, 0.f);
            ar2[kt][1] = make_float4(0.f, 0.f, 0.f, 0.f);
        }
    }

    // ---- K-loop, tile t0
    #pragma unroll
    for (int kt = 0; kt < NKT; ++kt) {
        float4 f0 = ar[kt][0], f1 = ar[kt][1];
        unsigned int au[4] = {pack2(f0.x, f0.y), pack2(f0.z, f0.w),
                              pack2(f1.x, f1.y), pack2(f1.z, f1.w)};
        s16x8 a = *(s16x8*)au;
        const unsigned short* bbase = &Bf[kt * NNT * 512];
        #pragma unroll
        for (int nt = 0; nt < NNT; ++nt) {
            s16x8 b = *(const s16x8*)(bbase + nt * 512 + lane * 8);
            acc[nt] = __builtin_amdgcn_mfma_f32_16x16x32_bf16(a, b, acc[nt], 0, 0, 0);
        }
    }

    // ---- epilogue, tile t0
    if (row0 >= NNODE) {
        #pragma unroll
        for (int nt = 0; nt < NNT; ++nt) {
            int col = nt * 16 + ln;
            if (nt < 12 || ln < 8) {
                float bv = bias[col];
                #pragma unroll
                for (int r = 0; r < 4; ++r)
                    out[(size_t)(row0 + quad * 4 + r) * FDIM + col] = acc[nt][r] + bv;
            }
        }
    } else {
        // --- fused k_av: a_s/a_d for this wave's 16 rows, from A registers.
        {
            float ps = 0.f, pd = 0.f;
            #pragma unroll
            for (int kt = 0; kt < NKT; ++kt) {
                if (kt < 6 || quad == 0) {
                    float4 f0 = ar[kt][0], f1 = ar[kt][1];
                    const float4* sp = (const float4*)(wsv + kt * 32 + quad * 8);
                    const float4* dp = (const float4*)(wdv + kt * 32 + quad * 8);
                    float4 s0 = sp[0], s1 = sp[1], d0 = dp[0], d1 = dp[1];
                    ps += f0.x*s0.x + f0.y*s0.y + f0.z*s0.z + f0.w*s0.w
                        + f1.x*s1.x + f1.y*s1.y + f1.z*s1.z + f1.w*s1.w;
                    pd += f0.x*d0.x + f0.y*d0.y + f0.z*d0.z + f0.w*d0.w
                        + f1.x*d1.x + f1.y*d1.y + f1.z*d1.z + f1.w*d1.w;
                }
            }
            ps += __shfl_down(ps, 32); ps += __shfl_down(ps, 16);
            pd += __shfl_down(pd, 32); pd += __shfl_down(pd, 16);
            if (lane < 16) {
                a_s[row0 + lane] = ps;
                a_d[row0 + lane] = pd;
            }
        }
        // --- h0frag: transpose C-layout -> bf16 B-fragment halves.
        float* scrw = &scr[w][0];
        const int kt2 = row0 >> 5;
        const int lo  = (row0 >> 4) & 1;
        for (int nt = 0; nt < NNT; ++nt) {
            #pragma unroll
            for (int r = 0; r < 4; ++r) scrw[(quad * 4 + r) * 17 + ln] = acc[nt][r];
            __syncthreads();
            if (lane < 32) {                   // half-frag: lane = oct*16 + n
                int oct = lane >> 4, nl = lane & 15;
                uint4 dv;
                dv.x = pack2(scrw[(oct * 8 + 0) * 17 + nl], scrw[(oct * 8 + 1) * 17 + nl]);
                dv.y = pack2(scrw[(oct * 8 + 2) * 17 + nl], scrw[(oct * 8 + 3) * 17 + nl]);
                dv.z = pack2(scrw[(oct * 8 + 4) * 17 + nl], scrw[(oct * 8 + 5) * 17 + nl]);
                dv.w = pack2(scrw[(oct * 8 + 6) * 17 + nl], scrw[(oct * 8 + 7) * 17 + nl]);
                *(uint4*)(h0frag + ((size_t)(kt2 * NNT + nt) * 64 + lo * 32 + lane) * 8) = dv;
            }
            __syncthreads();
        }
    }

    // ---- K-loop, tile t1 (A already in ar2; Bf unchanged)
    #pragma unroll
    for (int nt = 0; nt < NNT; ++nt) acc[nt] = (f32x4){0.f, 0.f, 0.f, 0.f};

    #pragma unroll
    for (int kt = 0; kt < NKT; ++kt) {
        float4 f0 = ar2[kt][0], f1 = ar2[kt][1];
        unsigned int au[4] = {pack2(f0.x, f0.y), pack2(f0.z, f0.w),
                              pack2(f1.x, f1.y), pack2(f1.z, f1.w)};
        s16x8 a = *(s16x8*)au;
        const unsigned short* bbase = &Bf[kt * NNT * 512];
        #pragma unroll
        for (int nt = 0; nt < NNT; ++nt) {
            s16x8 b = *(const s16x8*)(bbase + nt * 512 + lane * 8);
            acc[nt] = __builtin_amdgcn_mfma_f32_16x16x32_bf16(a, b, acc[nt], 0, 0, 0);
        }
    }

    // ---- epilogue, tile t1 (always a plain store tile)
    #pragma unroll
    for (int nt = 0; nt < NNT; ++nt) {
        int col = nt * 16 + ln;
        if (nt < 12 || ln < 8) {
            float bv = bias[col];
            #pragma unroll
            for (int r = 0; r < 4; ++r)
                out[(size_t)(row1 + quad * 4 + r) * FDIM + col] = acc[nt][r] + bv;
        }
    }
}

// ---------------------------------------------------------------------------
// k_attn: out0 = (alpha @ h0) + bias via MFMA. 256 blocks = 64 i-tiles x
// 4 nt-GROUPS (groups 0-2: 4 nt's, group 3: nt=12 alone) -- exactly 1 block
// per CU. afrag (stats + exp/pack) computed once per block and shared by all
// nt's of the group: per-i-tile redundancy drops 7 -> 4 copies vs R7.
// B-reads for 4 consecutive nt are one contiguous 4 KB span per kt2.
// 4 waves, j-split 8 kt2 each, cross-wave LDS reduce, wave 0 stores.
// ---------------------------------------------------------------------------
template<int NT>
__device__ __forceinline__ void attn_group(const unsigned short* __restrict__ h0frag,
                                           const float* __restrict__ a_s,
                                           const float* __restrict__ a_d,
                                           const float* __restrict__ bias,
                                           float* __restrict__ out,
                                           float* as_s, float* mls, float* rls,
                                           f32x4 (*red)[3][64],
                                           int i0, int ntbase, int tid)
{
    const int lane = tid & 63;
    const int w    = __builtin_amdgcn_readfirstlane(tid >> 6);
    const int ln   = lane & 15;
    const int quad = lane >> 4;

    #pragma unroll
    for (int i = 0; i < 4; ++i) as_s[tid + i * 256] = a_s[tid + i * 256];
    __syncthreads();

    // wave-redundant global max of a_s
    float mx = -1e30f;
    #pragma unroll
    for (int i = 0; i < 16; ++i) mx = fmaxf(mx, as_s[lane + i * 64]);
    #pragma unroll
    for (int off = 32; off; off >>= 1) mx = fmaxf(mx, __shfl_down(mx, off));
    mx = __shfl(mx, 0);

    // wave w: stats for rows w*4 .. w*4+3
    #pragma unroll
    for (int rr = 0; rr < 4; ++rr) {
        const int r  = w * 4 + rr;
        const float adr = a_d[i0 + r];
        const float mi  = lrelu(adr + mx);
        float sum = 0.f;
        #pragma unroll
        for (int i = 0; i < 16; ++i)
            sum += __expf(lrelu(adr + as_s[lane + i * 64]) - mi);
        #pragma unroll
        for (int off = 32; off; off >>= 1) sum += __shfl_down(sum, off);
        if (lane == 0) { mls[r] = mi; rls[r] = 1.0f / sum; }
    }
    __syncthreads();

    const float ad = a_d[i0 + ln];
    const float mi = mls[ln];

    f32x4 accA[NT], accB[NT];
    #pragma unroll
    for (int q = 0; q < NT; ++q) {
        accA[q] = (f32x4){0.f, 0.f, 0.f, 0.f};
        accB[q] = (f32x4){0.f, 0.f, 0.f, 0.f};
    }

    #pragma unroll
    for (int k8 = 0; k8 < 8; ++k8) {
        const int kt2 = w * 8 + k8;             // wave's j-quarter
        const float4* ap = (const float4*)(as_s + kt2 * 32 + quad * 8);
        float4 f0 = ap[0], f1 = ap[1];
        float e[8] = {f0.x, f0.y, f0.z, f0.w, f1.x, f1.y, f1.z, f1.w};
        #pragma unroll
        for (int j = 0; j < 8; ++j)
            e[j] = __expf(lrelu(ad + e[j]) - mi);
        unsigned int au[4] = {pack2(e[0], e[1]), pack2(e[2], e[3]),
                              pack2(e[4], e[5]), pack2(e[6], e[7])};
        s16x8 afrag = *(s16x8*)au;              // shared by all NT tiles
        const unsigned short* bb =
            h0frag + ((size_t)(kt2 * NNT + ntbase) * 64 + lane) * 8;
        #pragma unroll
        for (int q = 0; q < NT; ++q) {
            s16x8 b = *(const s16x8*)(bb + (size_t)q * 512);
            if (k8 & 1) accB[q] = __builtin_amdgcn_mfma_f32_16x16x32_bf16(afrag, b, accB[q], 0, 0, 0);
            else        accA[q] = __builtin_amdgcn_mfma_f32_16x16x32_bf16(afrag, b, accA[q], 0, 0, 0);
        }
    }

    f32x4 acc[NT];
    #pragma unroll
    for (int q = 0; q < NT; ++q) acc[q] = accA[q] + accB[q];
    if (w > 0) {
        #pragma unroll
        for (int q = 0; q < NT; ++q) red[q][w - 1][lane] = acc[q];
    }
    __syncthreads();

    if (w == 0) {
        #pragma unroll
        for (int q = 0; q < NT; ++q) {
            #pragma unroll
            for (int ww = 0; ww < 3; ++ww) acc[q] += red[q][ww][lane];
            const int ntg = ntbase + q;
            const int col = ntg * 16 + ln;
            if (ntg < 12 || ln < 8) {
                float bv = bias[col];
                #pragma unroll
                for (int r = 0; r < 4; ++r) {
                    float rl = rls[quad * 4 + r];
                    out[(size_t)(i0 + quad * 4 + r) * FDIM + col] = acc[q][r] * rl + bv;
                }
            }
        }
    }
}

__global__ __launch_bounds__(256) void k_attn(const unsigned short* __restrict__ h0frag,
                                              const float* __restrict__ a_s,
                                              const float* __restrict__ a_d,
                                              const float* __restrict__ bias,
                                              float* __restrict__ out)
{
    __shared__ __align__(16) float as_s[1024];
    __shared__ float mls[16];
    __shared__ float rls[16];
    __shared__ f32x4 red[4][3][64];
    const int tid = threadIdx.x;
    const int it  = blockIdx.x >> 2;            // 0..63 (16-row i-tiles)
    const int g   = blockIdx.x & 3;             // 0..3  (nt-group)
    const int i0  = it * 16;

    if (g < 3)
        attn_group<4>(h0frag, a_s, a_d, bias, out,
                      as_s, mls, rls, red, i0, g * 4, tid);
    else
        attn_group<1>(h0frag, a_s, a_d, bias, out,
                      as_s, mls, rls, red, i0, 12, tid);
}

// ---------------------------------------------------------------------------
extern "C" void kernel_launch(void* const* d_in, const int* in_sizes, int n_in,
                              void* d_out, int out_size, void* d_ws, size_t ws_size,
                              hipStream_t stream)
{
    const float* x       = (const float*)d_in[0];
    const float* W       = (const float*)d_in[1];
    const float* att_src = (const float*)d_in[2];
    const float* att_dst = (const float*)d_in[3];
    const float* bias    = (const float*)d_in[4];
    float* out = (float*)d_out;
    char*  wsb = (char*)d_ws;

    unsigned short* h0frag = (unsigned short*)(wsb + 0);       // 425,984 B
    float* a_s   = (float*)(wsb + 425984);
    float* a_d   = (float*)(wsb + 430080);
    unsigned short* fragW = (unsigned short*)(wsb + 442368);   // 93,184 B
    float* wsv   = (float*)(wsb + 535552);
    float* wdv   = (float*)(wsb + 536352);

    k_prep <<<291,      64, 0, stream>>>(W, att_src, att_dst, fragW, wsv, wdv);
    k_gemm <<<NBLK,    512, 0, stream>>>(x, fragW, bias, wsv, wdv, out, h0frag, a_s, a_d);
    k_attn <<<64 * 4,  256, 0, stream>>>(h0frag, a_s, a_d, bias, out);
}